// Round 1
// baseline (1833.495 us; speedup 1.0000x reference)
//
#include <hip/hip_runtime.h>

// Max-unpooling scatter-add:
//   out = zeros(total); out[ind[i]] += x[i]  for all i
// x: float32 [32,128,128,64] flat (N = 33,554,432)
// ind: int (flat indices into out, all < total = 134,217,728)
// out: float32, out_size = 134,217,728 (536.9 MB)

__global__ __launch_bounds__(256) void unpool_scatter_kernel(
    const float* __restrict__ x,
    const int* __restrict__ ind,
    float* __restrict__ out,
    int n4) {
  int i = blockIdx.x * blockDim.x + threadIdx.x;
  if (i >= n4) return;
  // Vectorized 16B loads: 4 values + 4 indices per thread.
  float4 v  = reinterpret_cast<const float4*>(x)[i];
  int4   id = reinterpret_cast<const int4*>(ind)[i];
  // Hardware fp32 global atomic add (global_atomic_add_f32); avoids the
  // CAS-loop fallback the compiler may emit for plain atomicAdd on float.
  unsafeAtomicAdd(&out[id.x], v.x);
  unsafeAtomicAdd(&out[id.y], v.y);
  unsafeAtomicAdd(&out[id.z], v.z);
  unsafeAtomicAdd(&out[id.w], v.w);
}

extern "C" void kernel_launch(void* const* d_in, const int* in_sizes, int n_in,
                              void* d_out, int out_size, void* d_ws, size_t ws_size,
                              hipStream_t stream) {
  const float* x   = (const float*)d_in[0];
  const int*   ind = (const int*)d_in[1];
  float*       out = (float*)d_out;

  const int n = in_sizes[0];          // 33,554,432 values (divisible by 4)
  const int n4 = n / 4;

  // Zero-init the output every call (harness does not re-poison/zero between
  // timed replays; scatter-add must start from zeros each time).
  hipMemsetAsync(d_out, 0, (size_t)out_size * sizeof(float), stream);

  const int block = 256;
  const int grid = (n4 + block - 1) / block;   // 32768 blocks
  unpool_scatter_kernel<<<grid, block, 0, stream>>>(x, ind, out, n4);
}

// Round 3
// 1739.473 us; speedup vs baseline: 1.0541x; 1.0541x over previous
//
#include <hip/hip_runtime.h>

// Max-unpooling scatter-add, range-filtered multi-pass version.
//   out = zeros(total); out[ind[i]] += x[i]
// x:   float32, N = 33,554,432
// ind: int32 (harness converts int64 -> int), values in [0, 134,217,728)
// out: float32, 134,217,728 elements (536.9 MB)
//
// Rationale: output region (537 MB) > L3 (256 MB); random atomics thrash
// HBM with partial-line RMWs. P=4 passes confine the active output window
// to 134 MB (L3-resident); input streams are re-read per pass with
// non-temporal loads so they don't evict the output window.

typedef float f32x4 __attribute__((ext_vector_type(4)));
typedef int   i32x4 __attribute__((ext_vector_type(4)));

__global__ __launch_bounds__(256) void unpool_scatter_range(
    const float* __restrict__ x,
    const int* __restrict__ ind,
    float* __restrict__ out,
    int n4, int lo, int hi) {
  int i = blockIdx.x * blockDim.x + threadIdx.x;
  if (i >= n4) return;
  // Non-temporal vector loads: streaming inputs, no reuse within a pass.
  f32x4 v  = __builtin_nontemporal_load(reinterpret_cast<const f32x4*>(x) + i);
  i32x4 id = __builtin_nontemporal_load(reinterpret_cast<const i32x4*>(ind) + i);
  // Only scatter indices inside this pass's output window.
  if (id.x >= lo && id.x < hi) unsafeAtomicAdd(&out[id.x], v.x);
  if (id.y >= lo && id.y < hi) unsafeAtomicAdd(&out[id.y], v.y);
  if (id.z >= lo && id.z < hi) unsafeAtomicAdd(&out[id.z], v.z);
  if (id.w >= lo && id.w < hi) unsafeAtomicAdd(&out[id.w], v.w);
}

extern "C" void kernel_launch(void* const* d_in, const int* in_sizes, int n_in,
                              void* d_out, int out_size, void* d_ws, size_t ws_size,
                              hipStream_t stream) {
  const float* x   = (const float*)d_in[0];
  const int*   ind = (const int*)d_in[1];
  float*       out = (float*)d_out;

  const int n  = in_sizes[0];   // 33,554,432 (divisible by 4)
  const int n4 = n / 4;

  // Zero-init output every call (scatter-add semantics; harness does not
  // re-zero between timed replays).
  (void)hipMemsetAsync(d_out, 0, (size_t)out_size * sizeof(float), stream);

  const int block = 256;
  const int grid  = (n4 + block - 1) / block;  // 32768 blocks per pass

  const int P = 4;
  const int R = (out_size + P - 1) / P;        // 33,554,432-element window
  for (int p = 0; p < P; ++p) {
    const int lo = p * R;
    const int hi = (p == P - 1) ? out_size : (p + 1) * R;
    unpool_scatter_range<<<grid, block, 0, stream>>>(x, ind, out, n4, lo, hi);
  }
}

// Round 4
// 1302.896 us; speedup vs baseline: 1.4072x; 1.3351x over previous
//
#include <hip/hip_runtime.h>

// Max-unpooling scatter-add WITHOUT global atomics.
//   out = zeros(total); out[ind[i]] += x[i]
// Measured: random 4B global fp32 atomics cap at ~19.4 G/s (~8/cycle chip,
// 1/cycle/XCD) regardless of L3 residency -> eliminate them.
//
// Plan: partition pairs by 16K-float output window (8192 buckets), exact
// slots via histogram+scan (no global atomics), then one block per bucket
// accumulates in 64 KB LDS (ds_add_f32) and writes its window densely.
//
// x:   float32, N = 33,554,432
// ind: int32, values in [0, 134,217,728)
// out: float32, 134,217,728 elems. Fully covered by dense windows -> no memset.

typedef float f32x4 __attribute__((ext_vector_type(4)));
typedef int   i32x4 __attribute__((ext_vector_type(4)));

#define NB      8192      // buckets
#define BFL     16384     // floats per bucket window (64 KB LDS)
#define LOG_BFL 14
#define T       512       // tiles (phase-1 blocks); per_tile = N/T = 65536

// ---- K1: per-tile histogram. M[t*NB + b] (row-major, coalesced writes) ----
__global__ __launch_bounds__(256) void k_hist(const int* __restrict__ ind,
                                              unsigned* __restrict__ M,
                                              int per_tile) {
  __shared__ unsigned h[NB];
  const int t = blockIdx.x;
  for (int i = threadIdx.x; i < NB; i += 256) h[i] = 0;
  __syncthreads();
  const i32x4* p = reinterpret_cast<const i32x4*>(ind) + (size_t)t * (per_tile / 4);
  for (int k = threadIdx.x; k < per_tile / 4; k += 256) {
    i32x4 id = p[k];
    atomicAdd(&h[((unsigned)id.x) >> LOG_BFL], 1u);
    atomicAdd(&h[((unsigned)id.y) >> LOG_BFL], 1u);
    atomicAdd(&h[((unsigned)id.z) >> LOG_BFL], 1u);
    atomicAdd(&h[((unsigned)id.w) >> LOG_BFL], 1u);
  }
  __syncthreads();
  unsigned* Mrow = M + (size_t)t * NB;
  for (int i = threadIdx.x; i < NB; i += 256) Mrow[i] = h[i];
}

// ---- K4: per-column (bucket) exclusive scan over tiles + column totals ----
// Thread b walks its column; a wave reads 64 consecutive b per row: coalesced.
__global__ __launch_bounds__(256) void k_colscan(const unsigned* __restrict__ M,
                                                 unsigned* __restrict__ Mscan,
                                                 unsigned* __restrict__ colsum) {
  const int b = blockIdx.x * 256 + threadIdx.x;
  unsigned run = 0;
  for (int t = 0; t < T; ++t) {
    unsigned v = M[(size_t)t * NB + b];
    Mscan[(size_t)t * NB + b] = run;
    run += v;
  }
  colsum[b] = run;
}

// ---- K3: exclusive scan of colsum[NB] -> base[NB+1] (single block) ----
__global__ __launch_bounds__(256) void k_scan(const unsigned* __restrict__ colsum,
                                              unsigned* __restrict__ base) {
  __shared__ unsigned part[256];
  const int tid = threadIdx.x;
  unsigned loc[NB / 256];
  unsigned s = 0;
  const unsigned* src = colsum + tid * (NB / 256);
  for (int j = 0; j < NB / 256; ++j) { loc[j] = src[j]; s += loc[j]; }
  part[tid] = s;
  __syncthreads();
  if (tid == 0) {
    unsigned run = 0;
    for (int i = 0; i < 256; ++i) { unsigned v = part[i]; part[i] = run; run += v; }
    base[NB] = run;  // == N
  }
  __syncthreads();
  unsigned run = part[tid];
  unsigned* dst = base + tid * (NB / 256);
  for (int j = 0; j < NB / 256; ++j) { dst[j] = run; run += loc[j]; }
}

// ---- K5: scatter pairs into bucket-grouped scratch (LDS cursors only) ----
__global__ __launch_bounds__(256) void k_scatter(const float* __restrict__ x,
                                                 const int* __restrict__ ind,
                                                 const unsigned* __restrict__ Mscan,
                                                 const unsigned* __restrict__ base,
                                                 float* __restrict__ vout,
                                                 unsigned short* __restrict__ lout,
                                                 int per_tile) {
  __shared__ unsigned cur[NB];
  const int t = blockIdx.x;
  for (int i = threadIdx.x; i < NB; i += 256)
    cur[i] = base[i] + Mscan[(size_t)t * NB + i];
  __syncthreads();
  const i32x4* pi = reinterpret_cast<const i32x4*>(ind) + (size_t)t * (per_tile / 4);
  const f32x4* pv = reinterpret_cast<const f32x4*>(x) + (size_t)t * (per_tile / 4);
  for (int k = threadIdx.x; k < per_tile / 4; k += 256) {
    i32x4 id = pi[k];
    f32x4 v  = pv[k];
    {
      unsigned b = (unsigned)id.x >> LOG_BFL;
      unsigned r = atomicAdd(&cur[b], 1u);
      vout[r] = v.x; lout[r] = (unsigned short)(id.x & (BFL - 1));
    }
    {
      unsigned b = (unsigned)id.y >> LOG_BFL;
      unsigned r = atomicAdd(&cur[b], 1u);
      vout[r] = v.y; lout[r] = (unsigned short)(id.y & (BFL - 1));
    }
    {
      unsigned b = (unsigned)id.z >> LOG_BFL;
      unsigned r = atomicAdd(&cur[b], 1u);
      vout[r] = v.z; lout[r] = (unsigned short)(id.z & (BFL - 1));
    }
    {
      unsigned b = (unsigned)id.w >> LOG_BFL;
      unsigned r = atomicAdd(&cur[b], 1u);
      vout[r] = v.w; lout[r] = (unsigned short)(id.w & (BFL - 1));
    }
  }
}

// ---- K6: one block per bucket: LDS accumulate + dense window write ----
__global__ __launch_bounds__(256) void k_accum(const float* __restrict__ vout,
                                               const unsigned short* __restrict__ lout,
                                               const unsigned* __restrict__ base,
                                               float* __restrict__ out) {
  __shared__ float w[BFL];  // 64 KB
  const int b = blockIdx.x;
  for (int i = threadIdx.x; i < BFL; i += 256) w[i] = 0.f;
  __syncthreads();
  const unsigned s = base[b], e = base[b + 1];
  for (unsigned i = s + threadIdx.x; i < e; i += 256)
    atomicAdd(&w[lout[i]], vout[i]);   // ds_add_f32, CU-local
  __syncthreads();
  f32x4* o = reinterpret_cast<f32x4*>(out + (size_t)b * BFL);
  const f32x4* w4 = reinterpret_cast<const f32x4*>(w);
  for (int i = threadIdx.x; i < BFL / 4; i += 256)
    __builtin_nontemporal_store(w4[i], o + i);
}

// ---- Fallback (ws too small / unexpected shape): R1 atomic scatter ----
__global__ __launch_bounds__(256) void unpool_scatter_kernel(
    const float* __restrict__ x, const int* __restrict__ ind,
    float* __restrict__ out, int n4) {
  int i = blockIdx.x * blockDim.x + threadIdx.x;
  if (i >= n4) return;
  f32x4 v  = reinterpret_cast<const f32x4*>(x)[i];
  i32x4 id = reinterpret_cast<const i32x4*>(ind)[i];
  unsafeAtomicAdd(&out[id.x], v.x);
  unsafeAtomicAdd(&out[id.y], v.y);
  unsafeAtomicAdd(&out[id.z], v.z);
  unsafeAtomicAdd(&out[id.w], v.w);
}

extern "C" void kernel_launch(void* const* d_in, const int* in_sizes, int n_in,
                              void* d_out, int out_size, void* d_ws, size_t ws_size,
                              hipStream_t stream) {
  const float* x   = (const float*)d_in[0];
  const int*   ind = (const int*)d_in[1];
  float*       out = (float*)d_out;
  const int n = in_sizes[0];  // 33,554,432

  // Workspace layout (256B-aligned sections):
  const size_t szM    = (size_t)T * NB * sizeof(unsigned);        // 16.78 MB
  const size_t szScan = szM;                                       // 16.78 MB
  const size_t szCol  = ((size_t)NB * sizeof(unsigned) + 255) & ~(size_t)255;
  const size_t szBase = ((size_t)(NB + 1) * sizeof(unsigned) + 255) & ~(size_t)255;
  const size_t szVal  = (size_t)n * sizeof(float);                 // 134.2 MB
  const size_t szLoc  = (size_t)n * sizeof(unsigned short);        // 67.1 MB
  const size_t need   = szM + szScan + szCol + szBase + szVal + szLoc;

  const bool shape_ok = (n % (T * 4) == 0) && ((size_t)out_size == (size_t)NB * BFL);

  if (!shape_ok || ws_size < need) {
    // Fallback: plain atomic scatter (measured ~1.77 ms).
    (void)hipMemsetAsync(d_out, 0, (size_t)out_size * sizeof(float), stream);
    const int n4 = n / 4;
    unpool_scatter_kernel<<<(n4 + 255) / 256, 256, 0, stream>>>(x, ind, out, n4);
    return;
  }

  char* ws = (char*)d_ws;
  unsigned*       M      = (unsigned*)(ws);
  unsigned*       Mscan  = (unsigned*)(ws + szM);
  unsigned*       colsum = (unsigned*)(ws + szM + szScan);
  unsigned*       base   = (unsigned*)(ws + szM + szScan + szCol);
  float*          vout   = (float*)(ws + szM + szScan + szCol + szBase);
  unsigned short* lout   = (unsigned short*)(ws + szM + szScan + szCol + szBase + szVal);

  const int per_tile = n / T;  // 65536

  k_hist   <<<T,        256, 0, stream>>>(ind, M, per_tile);
  k_colscan<<<NB / 256, 256, 0, stream>>>(M, Mscan, colsum);
  k_scan   <<<1,        256, 0, stream>>>(colsum, base);
  k_scatter<<<T,        256, 0, stream>>>(x, ind, Mscan, base, vout, lout, per_tile);
  k_accum  <<<NB,       256, 0, stream>>>(vout, lout, base, out);
  // Output fully covered by dense windows -> no memset needed.
}

// Round 5
// 882.487 us; speedup vs baseline: 2.0776x; 1.4764x over previous
//
#include <hip/hip_runtime.h>

// Max-unpooling scatter-add, two-level radix partition, no global atomics.
//   out = zeros(total); out[ind[i]] += x[i]
// N = 2^25 pairs, OUT = 2^27 floats (536.9 MB).
//
// R4 lesson: single-level 8192-bucket scatter had 10x write amplification
// (active partial lines >> L2). Fix: level-1 into 512 coarse buckets
// (2 KB runs/tile/bucket, active lines L2-resident), level-2 within each
// coarse bucket into 16 fine windows (32 KB runs). Pairs P1 live in the
// upper half of d_out (dead until k_accum rewrites everything).

typedef float f32x4 __attribute__((ext_vector_type(4)));
typedef int   i32x4 __attribute__((ext_vector_type(4)));

#define N_TOT   (1 << 25)   // input pairs
#define OUT_TOT (1 << 27)   // output floats
#define T1      256         // level-1 tiles
#define PT      (N_TOT / T1)   // 131072 pairs per tile
#define PT4     (PT / 4)       // 32768 vec4 per tile
#define NB1     512         // coarse buckets
#define CSH     18          // coarse = idx >> 18
#define NBF     8192        // fine buckets (global)
#define FSH     14          // fine = idx >> 14
#define FPC     16          // fines per coarse
#define WFL     16384       // floats per fine window (64 KB LDS)

// ---- K1: per-tile fine histogram (coarse derivable by summing 16) ----
__global__ __launch_bounds__(1024) void k_hist(const int* __restrict__ ind,
                                               unsigned* __restrict__ M1,
                                               unsigned* __restrict__ Mf) {
  __shared__ unsigned hf[NBF];  // 32 KB
  const int t = blockIdx.x;
  for (int i = threadIdx.x; i < NBF; i += 1024) hf[i] = 0;
  __syncthreads();
  const i32x4* p = reinterpret_cast<const i32x4*>(ind) + (size_t)t * PT4;
  for (int k = threadIdx.x; k < PT4; k += 1024) {
    i32x4 id = p[k];
    atomicAdd(&hf[(unsigned)id.x >> FSH], 1u);
    atomicAdd(&hf[(unsigned)id.y >> FSH], 1u);
    atomicAdd(&hf[(unsigned)id.z >> FSH], 1u);
    atomicAdd(&hf[(unsigned)id.w >> FSH], 1u);
  }
  __syncthreads();
  for (int b = threadIdx.x; b < NB1; b += 1024) {   // coarse counts
    unsigned s = 0;
    #pragma unroll
    for (int j = 0; j < FPC; ++j) s += hf[b * FPC + j];
    M1[(size_t)t * NB1 + b] = s;
  }
  for (int i = threadIdx.x; i < NBF; i += 1024) Mf[(size_t)t * NBF + i] = hf[i];
}

// ---- K2: fine column sums over tiles ----
__global__ __launch_bounds__(256) void k_colsumf(const unsigned* __restrict__ Mf,
                                                 unsigned* __restrict__ csf) {
  const int f = blockIdx.x * 256 + threadIdx.x;
  unsigned s = 0;
  for (int t = 0; t < T1; ++t) s += Mf[(size_t)t * NBF + f];
  csf[f] = s;
}

// ---- K3: exclusive scan csf[8192] -> fb[8193] (single block) ----
__global__ __launch_bounds__(256) void k_scanfb(const unsigned* __restrict__ csf,
                                               unsigned* __restrict__ fb) {
  __shared__ unsigned part[256];
  const int tid = threadIdx.x;
  unsigned loc[NBF / 256];
  unsigned s = 0;
  const unsigned* src = csf + tid * (NBF / 256);
  for (int j = 0; j < NBF / 256; ++j) { loc[j] = src[j]; s += loc[j]; }
  part[tid] = s;
  __syncthreads();
  if (tid == 0) {
    unsigned run = 0;
    for (int i = 0; i < 256; ++i) { unsigned v = part[i]; part[i] = run; run += v; }
    fb[NBF] = run;  // == N_TOT
  }
  __syncthreads();
  unsigned run = part[tid];
  unsigned* dst = fb + tid * (NBF / 256);
  for (int j = 0; j < NBF / 256; ++j) { dst[j] = run; run += loc[j]; }
}

// ---- K4: level-1 scatter into coarse-ordered (val,idx) pairs ----
// Per-block cursor = fb[b*FPC] + sum_{t'<t} M1[t'][b] (prefix computed here;
// avoids a latency-bound 512-thread column-scan kernel).
__global__ __launch_bounds__(1024) void k_scatter1(const float* __restrict__ x,
                                                   const int* __restrict__ ind,
                                                   const unsigned* __restrict__ M1,
                                                   const unsigned* __restrict__ fb,
                                                   uint2* __restrict__ P1) {
  __shared__ unsigned cur[NB1];
  const int t = blockIdx.x;
  for (int b = threadIdx.x; b < NB1; b += 1024) {
    unsigned s = fb[b * FPC];
    for (int t2 = 0; t2 < t; ++t2) s += M1[(size_t)t2 * NB1 + b];
    cur[b] = s;
  }
  __syncthreads();
  const i32x4* pi = reinterpret_cast<const i32x4*>(ind) + (size_t)t * PT4;
  const f32x4* pv = reinterpret_cast<const f32x4*>(x) + (size_t)t * PT4;
  for (int k = threadIdx.x; k < PT4; k += 1024) {
    i32x4 id = pi[k];
    f32x4 v  = pv[k];
    unsigned r;
    r = atomicAdd(&cur[(unsigned)id.x >> CSH], 1u);
    P1[r] = make_uint2(__float_as_uint(v.x), (unsigned)id.x);
    r = atomicAdd(&cur[(unsigned)id.y >> CSH], 1u);
    P1[r] = make_uint2(__float_as_uint(v.y), (unsigned)id.y);
    r = atomicAdd(&cur[(unsigned)id.z >> CSH], 1u);
    P1[r] = make_uint2(__float_as_uint(v.z), (unsigned)id.z);
    r = atomicAdd(&cur[(unsigned)id.w >> CSH], 1u);
    P1[r] = make_uint2(__float_as_uint(v.w), (unsigned)id.w);
  }
}

// ---- K5: level-2 scatter, one block per coarse bucket -> 16 fine runs ----
__global__ __launch_bounds__(1024) void k_scatter2(const uint2* __restrict__ P1,
                                                   const unsigned* __restrict__ fb,
                                                   float* __restrict__ vout2,
                                                   unsigned short* __restrict__ lout2) {
  __shared__ unsigned cur[FPC];
  const int c = blockIdx.x;
  if (threadIdx.x < FPC) cur[threadIdx.x] = fb[c * FPC + threadIdx.x];
  __syncthreads();
  const unsigned s = fb[c * FPC];
  const unsigned e = fb[c * FPC + FPC];   // fb[8192] == N for c==511
  for (unsigned i = s + threadIdx.x; i < e; i += 1024) {
    uint2 p = P1[i];
    unsigned f = (p.y >> FSH) & (FPC - 1);
    unsigned r = atomicAdd(&cur[f], 1u);
    vout2[r] = __uint_as_float(p.x);
    lout2[r] = (unsigned short)(p.y & (WFL - 1));
  }
}

// ---- K6: one block per fine window: LDS accumulate + dense write ----
__global__ __launch_bounds__(256) void k_accum(const float* __restrict__ vout2,
                                               const unsigned short* __restrict__ lout2,
                                               const unsigned* __restrict__ fb,
                                               float* __restrict__ out) {
  __shared__ float w[WFL];  // 64 KB
  const int f = blockIdx.x;
  for (int i = threadIdx.x; i < WFL; i += 256) w[i] = 0.f;
  __syncthreads();
  const unsigned s = fb[f], e = fb[f + 1];
  for (unsigned i = s + threadIdx.x; i < e; i += 256)
    atomicAdd(&w[lout2[i]], vout2[i]);   // ds_add_f32, CU-local
  __syncthreads();
  f32x4* o = reinterpret_cast<f32x4*>(out + (size_t)f * WFL);
  const f32x4* w4 = reinterpret_cast<const f32x4*>(w);
  for (int i = threadIdx.x; i < WFL / 4; i += 256)
    __builtin_nontemporal_store(w4[i], o + i);
}

// ---- Fallback: plain atomic scatter (measured ~1.77 ms) ----
__global__ __launch_bounds__(256) void unpool_scatter_kernel(
    const float* __restrict__ x, const int* __restrict__ ind,
    float* __restrict__ out, int n4) {
  int i = blockIdx.x * blockDim.x + threadIdx.x;
  if (i >= n4) return;
  f32x4 v  = reinterpret_cast<const f32x4*>(x)[i];
  i32x4 id = reinterpret_cast<const i32x4*>(ind)[i];
  unsafeAtomicAdd(&out[id.x], v.x);
  unsafeAtomicAdd(&out[id.y], v.y);
  unsafeAtomicAdd(&out[id.z], v.z);
  unsafeAtomicAdd(&out[id.w], v.w);
}

extern "C" void kernel_launch(void* const* d_in, const int* in_sizes, int n_in,
                              void* d_out, int out_size, void* d_ws, size_t ws_size,
                              hipStream_t stream) {
  const float* x   = (const float*)d_in[0];
  const int*   ind = (const int*)d_in[1];
  float*       out = (float*)d_out;
  const int n = in_sizes[0];

  // Workspace layout (ws): M1 | Mf | csf | fb | vout2 | lout2
  const size_t szM1  = (size_t)T1 * NB1 * sizeof(unsigned);      // 512 KB
  const size_t szMf  = (size_t)T1 * NBF * sizeof(unsigned);      // 8 MB
  const size_t szCsf = ((size_t)NBF * sizeof(unsigned) + 255) & ~(size_t)255;
  const size_t szFb  = ((size_t)(NBF + 1) * sizeof(unsigned) + 255) & ~(size_t)255;
  const size_t szV2  = (size_t)N_TOT * sizeof(float);            // 134.2 MB
  const size_t szL2  = (size_t)N_TOT * sizeof(unsigned short);   // 67.1 MB
  const size_t need  = szM1 + szMf + szCsf + szFb + szV2 + szL2; // ~210 MB

  const bool shape_ok = (n == N_TOT) && (out_size == OUT_TOT);

  if (!shape_ok || ws_size < need) {
    (void)hipMemsetAsync(d_out, 0, (size_t)out_size * sizeof(float), stream);
    const int n4 = n / 4;
    unpool_scatter_kernel<<<(n4 + 255) / 256, 256, 0, stream>>>(x, ind, out, n4);
    return;
  }

  char* ws = (char*)d_ws;
  unsigned*       M1    = (unsigned*)(ws);
  unsigned*       Mf    = (unsigned*)(ws + szM1);
  unsigned*       csf   = (unsigned*)(ws + szM1 + szMf);
  unsigned*       fb    = (unsigned*)(ws + szM1 + szMf + szCsf);
  float*          vout2 = (float*)(ws + szM1 + szMf + szCsf + szFb);
  unsigned short* lout2 = (unsigned short*)(ws + szM1 + szMf + szCsf + szFb + szV2);

  // P1 (coarse-ordered pairs, 8B x N = 268 MB) lives in the UPPER HALF of
  // d_out: dead storage until k_accum (which runs after k_scatter2 has
  // fully consumed P1, stream-ordered) rewrites all of out densely.
  uint2* P1 = reinterpret_cast<uint2*>(out + (size_t)(OUT_TOT / 2));

  k_hist    <<<T1,        1024, 0, stream>>>(ind, M1, Mf);
  k_colsumf <<<NBF / 256,  256, 0, stream>>>(Mf, csf);
  k_scanfb  <<<1,          256, 0, stream>>>(csf, fb);
  k_scatter1<<<T1,        1024, 0, stream>>>(x, ind, M1, fb, P1);
  k_scatter2<<<NB1,       1024, 0, stream>>>(P1, fb, vout2, lout2);
  k_accum   <<<NBF,        256, 0, stream>>>(vout2, lout2, fb, out);
  // Output fully covered by dense windows -> no memset needed.
}

// Round 6
// 585.563 us; speedup vs baseline: 3.1312x; 1.5071x over previous
//
#include <hip/hip_runtime.h>

// Max-unpooling scatter-add, two-level radix partition with LDS batch-sort
// (software write-combining), no global atomics.
//   out = zeros(total); out[ind[i]] += x[i]
// N = 2^25 pairs, OUT = 2^27 floats (536.9 MB).
//
// R5 lesson: per-lane scattered 8-B stores = 1 L2 transaction per 8 B and
// partial-line evictions (WRITE 760 MB vs 268 ideal, 2.56 TB/s). Fix: rank
// each 8192-pair batch into a sorted LDS buffer, then write per-bucket
// segments sequentially -> wave-coalesced full-line stores.

typedef float f32x4 __attribute__((ext_vector_type(4)));
typedef int   i32x4 __attribute__((ext_vector_type(4)));

#define N_TOT   (1 << 25)    // input pairs
#define OUT_TOT (1 << 27)    // output floats
#define T1      512          // level-1 tiles
#define PT      (N_TOT / T1) // 65536 pairs per tile
#define PT4     (PT / 4)     // 16384 vec4 per tile
#define NB1     256          // coarse buckets (frontier 256 lines/block -> L2-safe)
#define CSH     19           // coarse = idx >> 19
#define NBF     8192         // fine buckets
#define FSH     14           // fine = idx >> 14
#define FPC     32           // fines per coarse
#define WFL     16384        // floats per fine window (64 KB LDS)
#define BATCH   8192         // pairs per sort batch (64 KB LDS buffer)

// ---- K1: per-tile fine histogram; coarse counts derived by summing 32 ----
__global__ __launch_bounds__(1024) void k_hist(const int* __restrict__ ind,
                                               unsigned* __restrict__ M1,
                                               unsigned* __restrict__ Mf) {
  __shared__ unsigned hf[NBF];  // 32 KB
  const int t = blockIdx.x;
  for (int i = threadIdx.x; i < NBF; i += 1024) hf[i] = 0;
  __syncthreads();
  const i32x4* p = reinterpret_cast<const i32x4*>(ind) + (size_t)t * PT4;
  for (int k = threadIdx.x; k < PT4; k += 1024) {
    i32x4 id = p[k];   // cached: ind is re-read by k_scatter1 (L3 reuse)
    atomicAdd(&hf[(unsigned)id.x >> FSH], 1u);
    atomicAdd(&hf[(unsigned)id.y >> FSH], 1u);
    atomicAdd(&hf[(unsigned)id.z >> FSH], 1u);
    atomicAdd(&hf[(unsigned)id.w >> FSH], 1u);
  }
  __syncthreads();
  for (int b = threadIdx.x; b < NB1; b += 1024) {
    unsigned s = 0;
    #pragma unroll
    for (int j = 0; j < FPC; ++j) s += hf[b * FPC + j];
    M1[(size_t)t * NB1 + b] = s;
  }
  for (int i = threadIdx.x; i < NBF; i += 1024) Mf[(size_t)t * NBF + i] = hf[i];
}

// ---- K2: fine column sums over tiles ----
__global__ __launch_bounds__(256) void k_colsumf(const unsigned* __restrict__ Mf,
                                                 unsigned* __restrict__ csf) {
  const int f = blockIdx.x * 256 + threadIdx.x;
  unsigned s = 0;
  for (int t = 0; t < T1; ++t) s += Mf[(size_t)t * NBF + f];
  csf[f] = s;
}

// ---- K3: exclusive scan csf[8192] -> fb[8193] ----
__global__ __launch_bounds__(256) void k_scanfb(const unsigned* __restrict__ csf,
                                                unsigned* __restrict__ fb) {
  __shared__ unsigned part[256];
  const int tid = threadIdx.x;
  unsigned loc[NBF / 256];
  unsigned s = 0;
  const unsigned* src = csf + tid * (NBF / 256);
  for (int j = 0; j < NBF / 256; ++j) { loc[j] = src[j]; s += loc[j]; }
  part[tid] = s;
  __syncthreads();
  if (tid == 0) {
    unsigned run = 0;
    for (int i = 0; i < 256; ++i) { unsigned v = part[i]; part[i] = run; run += v; }
    fb[NBF] = run;  // == N_TOT
  }
  __syncthreads();
  unsigned run = part[tid];
  unsigned* dst = fb + tid * (NBF / 256);
  for (int j = 0; j < NBF / 256; ++j) { dst[j] = run; run += loc[j]; }
}

// ---- K4: per-tile exclusive scan of coarse counts over tiles ----
__global__ __launch_bounds__(256) void k_colscan1(const unsigned* __restrict__ M1,
                                                  unsigned* __restrict__ Mscan1) {
  const int b = threadIdx.x;  // 256 threads, 1 block
  unsigned run = 0;
  for (int t = 0; t < T1; ++t) {
    unsigned v = M1[(size_t)t * NB1 + b];
    Mscan1[(size_t)t * NB1 + b] = run;
    run += v;
  }
}

// ---- K5: level-1 scatter with LDS batch-sort -> coalesced segment writes ----
__global__ __launch_bounds__(1024) void k_scatter1(const float* __restrict__ x,
                                                   const int* __restrict__ ind,
                                                   const unsigned* __restrict__ Mscan1,
                                                   const unsigned* __restrict__ fb,
                                                   uint2* __restrict__ P1) {
  __shared__ uint2    sbuf[BATCH];   // 64 KB
  __shared__ unsigned hist[NB1], sbase[NB1], cur[NB1];
  const int t = blockIdx.x;
  if (threadIdx.x < NB1)
    cur[threadIdx.x] = fb[threadIdx.x * FPC] + Mscan1[(size_t)t * NB1 + threadIdx.x];
  const i32x4* pi = reinterpret_cast<const i32x4*>(ind) + (size_t)t * PT4;
  const f32x4* pv = reinterpret_cast<const f32x4*>(x)  + (size_t)t * PT4;

  for (int bt = 0; bt < PT / BATCH; ++bt) {           // 8 batches
    const int v0 = bt * (BATCH / 4);                  // vec4 base of batch
    // load 8 pairs/thread (2 vec4 of idx + val); x is read-once -> NT
    i32x4 iA = pi[v0 + threadIdx.x];
    f32x4 vA = __builtin_nontemporal_load(pv + v0 + threadIdx.x);
    i32x4 iB = pi[v0 + 1024 + threadIdx.x];
    f32x4 vB = __builtin_nontemporal_load(pv + v0 + 1024 + threadIdx.x);
    if (threadIdx.x < NB1) hist[threadIdx.x] = 0;
    __syncthreads();
    // rank within batch per bucket (LDS atomics)
    unsigned rA0 = atomicAdd(&hist[(unsigned)iA.x >> CSH], 1u);
    unsigned rA1 = atomicAdd(&hist[(unsigned)iA.y >> CSH], 1u);
    unsigned rA2 = atomicAdd(&hist[(unsigned)iA.z >> CSH], 1u);
    unsigned rA3 = atomicAdd(&hist[(unsigned)iA.w >> CSH], 1u);
    unsigned rB0 = atomicAdd(&hist[(unsigned)iB.x >> CSH], 1u);
    unsigned rB1 = atomicAdd(&hist[(unsigned)iB.y >> CSH], 1u);
    unsigned rB2 = atomicAdd(&hist[(unsigned)iB.z >> CSH], 1u);
    unsigned rB3 = atomicAdd(&hist[(unsigned)iB.w >> CSH], 1u);
    __syncthreads();
    // exclusive scan of hist[256] by one wave (4 entries/lane + shfl scan)
    if (threadIdx.x < 64) {
      const unsigned lane = threadIdx.x;
      unsigned h0 = hist[4 * lane], h1 = hist[4 * lane + 1];
      unsigned h2 = hist[4 * lane + 2], h3 = hist[4 * lane + 3];
      unsigned sum = h0 + h1 + h2 + h3;
      unsigned inc = sum;
      for (int off = 1; off < 64; off <<= 1) {
        unsigned o = __shfl_up(inc, off, 64);
        if (lane >= (unsigned)off) inc += o;
      }
      unsigned exc = inc - sum;
      sbase[4 * lane]     = exc;
      sbase[4 * lane + 1] = exc + h0;
      sbase[4 * lane + 2] = exc + h0 + h1;
      sbase[4 * lane + 3] = exc + h0 + h1 + h2;
    }
    __syncthreads();
    // place pairs into sorted LDS buffer
    sbuf[sbase[(unsigned)iA.x >> CSH] + rA0] = make_uint2(__float_as_uint(vA.x), (unsigned)iA.x);
    sbuf[sbase[(unsigned)iA.y >> CSH] + rA1] = make_uint2(__float_as_uint(vA.y), (unsigned)iA.y);
    sbuf[sbase[(unsigned)iA.z >> CSH] + rA2] = make_uint2(__float_as_uint(vA.z), (unsigned)iA.z);
    sbuf[sbase[(unsigned)iA.w >> CSH] + rA3] = make_uint2(__float_as_uint(vA.w), (unsigned)iA.w);
    sbuf[sbase[(unsigned)iB.x >> CSH] + rB0] = make_uint2(__float_as_uint(vB.x), (unsigned)iB.x);
    sbuf[sbase[(unsigned)iB.y >> CSH] + rB1] = make_uint2(__float_as_uint(vB.y), (unsigned)iB.y);
    sbuf[sbase[(unsigned)iB.z >> CSH] + rB2] = make_uint2(__float_as_uint(vB.z), (unsigned)iB.z);
    sbuf[sbase[(unsigned)iB.w >> CSH] + rB3] = make_uint2(__float_as_uint(vB.w), (unsigned)iB.w);
    __syncthreads();
    // write sorted batch out: consecutive j -> consecutive global dst
    #pragma unroll
    for (int k = 0; k < BATCH / 1024; ++k) {
      unsigned j = (unsigned)(k * 1024 + threadIdx.x);
      uint2 q = sbuf[j];
      unsigned b = q.y >> CSH;
      P1[cur[b] + (j - sbase[b])] = q;   // cacheable: P1 re-read by scatter2
    }
    __syncthreads();
    if (threadIdx.x < NB1) cur[threadIdx.x] += hist[threadIdx.x];
    __syncthreads();
  }
}

// ---- K6: level-2 scatter, block per coarse bucket, LDS batch-sort x32 ----
__global__ __launch_bounds__(1024) void k_scatter2(const uint2* __restrict__ P1,
                                                   const unsigned* __restrict__ fb,
                                                   float* __restrict__ vout2,
                                                   unsigned short* __restrict__ lout2) {
  __shared__ uint2    sbuf[BATCH];   // 64 KB
  __shared__ unsigned hist[FPC], sbase[FPC], cur[FPC];
  const int c = blockIdx.x;
  const unsigned s = fb[c * FPC];
  const unsigned e = fb[c * FPC + FPC];
  if (threadIdx.x < FPC) cur[threadIdx.x] = fb[c * FPC + threadIdx.x];

  for (unsigned bs = s; bs < e; bs += BATCH) {
    const unsigned len = min((unsigned)BATCH, e - bs);
    uint2 p[8]; unsigned r[8];
    if (threadIdx.x < FPC) hist[threadIdx.x] = 0;
    __syncthreads();
    #pragma unroll
    for (int k = 0; k < 8; ++k) {
      unsigned j = (unsigned)threadIdx.x + (unsigned)k * 1024u;
      if (j < len) {
        p[k] = P1[bs + j];
        r[k] = atomicAdd(&hist[(p[k].y >> FSH) & (FPC - 1)], 1u);
      }
    }
    __syncthreads();
    if (threadIdx.x < 32) {   // scan 32 entries in one 32-wide shfl segment
      const unsigned lane = threadIdx.x;
      unsigned h = hist[lane];
      unsigned inc = h;
      for (int off = 1; off < 32; off <<= 1) {
        unsigned o = __shfl_up(inc, off, 32);
        if (lane >= (unsigned)off) inc += o;
      }
      sbase[lane] = inc - h;
    }
    __syncthreads();
    #pragma unroll
    for (int k = 0; k < 8; ++k) {
      unsigned j = (unsigned)threadIdx.x + (unsigned)k * 1024u;
      if (j < len) sbuf[sbase[(p[k].y >> FSH) & (FPC - 1)] + r[k]] = p[k];
    }
    __syncthreads();
    for (unsigned j = threadIdx.x; j < len; j += 1024) {
      uint2 q = sbuf[j];
      unsigned f = (q.y >> FSH) & (FPC - 1);
      unsigned d = cur[f] + (j - sbase[f]);
      vout2[d] = __uint_as_float(q.x);                  // cacheable: accum re-reads
      lout2[d] = (unsigned short)(q.y & (WFL - 1));
    }
    __syncthreads();
    if (threadIdx.x < FPC) cur[threadIdx.x] += hist[threadIdx.x];
    __syncthreads();
  }
}

// ---- K7: one block per fine window: LDS accumulate + dense write ----
__global__ __launch_bounds__(512) void k_accum(const float* __restrict__ vout2,
                                               const unsigned short* __restrict__ lout2,
                                               const unsigned* __restrict__ fb,
                                               float* __restrict__ out) {
  __shared__ float w[WFL];  // 64 KB
  const int f = blockIdx.x;
  f32x4* w4 = reinterpret_cast<f32x4*>(w);
  for (int i = threadIdx.x; i < WFL / 4; i += 512) w4[i] = (f32x4){0.f, 0.f, 0.f, 0.f};
  __syncthreads();
  const unsigned s = fb[f], e = fb[f + 1];
  for (unsigned i = s + threadIdx.x; i < e; i += 512)
    atomicAdd(&w[lout2[i]], vout2[i]);   // ds_add_f32, CU-local
  __syncthreads();
  f32x4* o = reinterpret_cast<f32x4*>(out + (size_t)f * WFL);
  for (int i = threadIdx.x; i < WFL / 4; i += 512)
    __builtin_nontemporal_store(w4[i], o + i);
}

// ---- Fallback: plain atomic scatter (measured ~1.77 ms) ----
__global__ __launch_bounds__(256) void unpool_scatter_kernel(
    const float* __restrict__ x, const int* __restrict__ ind,
    float* __restrict__ out, int n4) {
  int i = blockIdx.x * blockDim.x + threadIdx.x;
  if (i >= n4) return;
  f32x4 v  = reinterpret_cast<const f32x4*>(x)[i];
  i32x4 id = reinterpret_cast<const i32x4*>(ind)[i];
  unsafeAtomicAdd(&out[id.x], v.x);
  unsafeAtomicAdd(&out[id.y], v.y);
  unsafeAtomicAdd(&out[id.z], v.z);
  unsafeAtomicAdd(&out[id.w], v.w);
}

extern "C" void kernel_launch(void* const* d_in, const int* in_sizes, int n_in,
                              void* d_out, int out_size, void* d_ws, size_t ws_size,
                              hipStream_t stream) {
  const float* x   = (const float*)d_in[0];
  const int*   ind = (const int*)d_in[1];
  float*       out = (float*)d_out;
  const int n = in_sizes[0];

  // ws layout: M1 | Mscan1 | csf | fb | vout2 | lout2  (~203 MB)
  const size_t szM1  = (size_t)T1 * NB1 * sizeof(unsigned);      // 512 KB
  const size_t szMs  = szM1;                                      // 512 KB
  const size_t szCsf = ((size_t)NBF * sizeof(unsigned) + 255) & ~(size_t)255;
  const size_t szFb  = ((size_t)(NBF + 1) * sizeof(unsigned) + 255) & ~(size_t)255;
  const size_t szV2  = (size_t)N_TOT * sizeof(float);             // 134.2 MB
  const size_t szL2  = (size_t)N_TOT * sizeof(unsigned short);    // 67.1 MB
  const size_t need  = szM1 + szMs + szCsf + szFb + szV2 + szL2;

  const bool shape_ok = (n == N_TOT) && (out_size == OUT_TOT);

  if (!shape_ok || ws_size < need) {
    (void)hipMemsetAsync(d_out, 0, (size_t)out_size * sizeof(float), stream);
    const int n4 = n / 4;
    unpool_scatter_kernel<<<(n4 + 255) / 256, 256, 0, stream>>>(x, ind, out, n4);
    return;
  }

  char* ws = (char*)d_ws;
  unsigned*       M1     = (unsigned*)(ws);
  unsigned*       Mscan1 = (unsigned*)(ws + szM1);
  unsigned*       csf    = (unsigned*)(ws + szM1 + szMs);
  unsigned*       fb     = (unsigned*)(ws + szM1 + szMs + szCsf);
  float*          vout2  = (float*)(ws + szM1 + szMs + szCsf + szFb);
  unsigned short* lout2  = (unsigned short*)(ws + szM1 + szMs + szCsf + szFb + szV2);

  // Dead-until-k_accum regions of d_out used as scratch:
  //   Mf (per-tile fine hist, 16.8 MB) -> lower region of out
  //   P1 (coarse-ordered pairs, 268 MB) -> upper half of out
  // Both fully consumed before k_accum rewrites all of out densely.
  unsigned* Mf = (unsigned*)out;
  uint2*    P1 = reinterpret_cast<uint2*>(out + (size_t)(OUT_TOT / 2));

  k_hist    <<<T1,        1024, 0, stream>>>(ind, M1, Mf);
  k_colsumf <<<NBF / 256,  256, 0, stream>>>(Mf, csf);
  k_scanfb  <<<1,          256, 0, stream>>>(csf, fb);
  k_colscan1<<<1,          256, 0, stream>>>(M1, Mscan1);
  k_scatter1<<<T1,        1024, 0, stream>>>(x, ind, Mscan1, fb, P1);
  k_scatter2<<<NB1,       1024, 0, stream>>>(P1, fb, vout2, lout2);
  k_accum   <<<NBF,        512, 0, stream>>>(vout2, lout2, fb, out);
  // Output fully covered by dense windows -> no memset needed.
}

// Round 7
// 542.329 us; speedup vs baseline: 3.3808x; 1.0797x over previous
//
#include <hip/hip_runtime.h>

// Max-unpooling scatter-add, two-level radix partition with LDS batch-sort
// (software write-combining), no global atomics.
//   out = zeros(total); out[ind[i]] += x[i]
// N = 2^25 pairs, OUT = 2^27 floats (536.9 MB).
//
// Pipeline: hist (fine histogram, coarse counts) -> scans -> scatter1
// (coarse-sort into P1, LDS batch-sort for coalesced writes) -> scatter2
// (fine-sort within coarse, same trick) -> accum (64 KB LDS window + dense
// write). ws is ~2.1 GB so all scratch lives there.

typedef float f32x4 __attribute__((ext_vector_type(4)));
typedef int   i32x4 __attribute__((ext_vector_type(4)));
typedef unsigned u32x2 __attribute__((ext_vector_type(2)));

#define N_TOT   (1 << 25)    // input pairs
#define OUT_TOT (1 << 27)    // output floats
#define T1      1024         // level-1 tiles
#define PT      (N_TOT / T1) // 32768 pairs per tile
#define PT4     (PT / 4)     // 8192 vec4 per tile
#define NB1     256          // coarse buckets
#define CSH     19           // coarse = idx >> 19
#define NBF     8192         // fine buckets
#define FSH     14           // fine = idx >> 14
#define FPC     32           // fines per coarse
#define WFL     16384        // floats per fine window (64 KB LDS)
#define BATCH   8192         // pairs per sort batch (64 KB LDS buffer)

// ---- K1: per-tile fine histogram (u16 out); coarse counts by summing ----
__global__ __launch_bounds__(1024) void k_hist(const int* __restrict__ ind,
                                               unsigned* __restrict__ M1,
                                               unsigned short* __restrict__ Mf) {
  __shared__ unsigned hf[NBF];  // 32 KB
  const int t = blockIdx.x;
  for (int i = threadIdx.x; i < NBF; i += 1024) hf[i] = 0;
  __syncthreads();
  const i32x4* p = reinterpret_cast<const i32x4*>(ind) + (size_t)t * PT4;
  for (int k = threadIdx.x; k < PT4; k += 1024) {
    i32x4 id = p[k];   // cacheable: ind re-read by scatter1 (L3 reuse)
    atomicAdd(&hf[(unsigned)id.x >> FSH], 1u);
    atomicAdd(&hf[(unsigned)id.y >> FSH], 1u);
    atomicAdd(&hf[(unsigned)id.z >> FSH], 1u);
    atomicAdd(&hf[(unsigned)id.w >> FSH], 1u);
  }
  __syncthreads();
  for (int b = threadIdx.x; b < NB1; b += 1024) {
    unsigned s = 0;
    #pragma unroll
    for (int j = 0; j < FPC; ++j) s += hf[b * FPC + j];
    M1[(size_t)t * NB1 + b] = s;
  }
  for (int i = threadIdx.x; i < NBF; i += 1024)
    Mf[(size_t)t * NBF + i] = (unsigned short)hf[i];  // max ~30 << 65535
}

// ---- K2: fine column sums over tiles ----
__global__ __launch_bounds__(256) void k_colsumf(const unsigned short* __restrict__ Mf,
                                                 unsigned* __restrict__ csf) {
  const int f = blockIdx.x * 256 + threadIdx.x;
  unsigned s = 0;
  for (int t = 0; t < T1; ++t) s += Mf[(size_t)t * NBF + f];
  csf[f] = s;
}

// ---- K3: exclusive scan csf[8192] -> fb[8193] ----
__global__ __launch_bounds__(256) void k_scanfb(const unsigned* __restrict__ csf,
                                                unsigned* __restrict__ fb) {
  __shared__ unsigned part[256];
  const int tid = threadIdx.x;
  unsigned loc[NBF / 256];
  unsigned s = 0;
  const unsigned* src = csf + tid * (NBF / 256);
  for (int j = 0; j < NBF / 256; ++j) { loc[j] = src[j]; s += loc[j]; }
  part[tid] = s;
  __syncthreads();
  if (tid == 0) {
    unsigned run = 0;
    for (int i = 0; i < 256; ++i) { unsigned v = part[i]; part[i] = run; run += v; }
    fb[NBF] = run;  // == N_TOT
  }
  __syncthreads();
  unsigned run = part[tid];
  unsigned* dst = fb + tid * (NBF / 256);
  for (int j = 0; j < NBF / 256; ++j) { dst[j] = run; run += loc[j]; }
}

// ---- K4: per-bucket exclusive scan of coarse counts over tiles ----
// Grid NB1 blocks; block b scans M1[:,b] over T1=1024 tiles in parallel.
__global__ __launch_bounds__(256) void k_colscan1(const unsigned* __restrict__ M1,
                                                  unsigned* __restrict__ Mscan1) {
  __shared__ unsigned part[256];
  const int b = blockIdx.x;
  const int tid = threadIdx.x;
  unsigned v[4];
  unsigned s = 0;
  #pragma unroll
  for (int j = 0; j < 4; ++j) {
    v[j] = M1[(size_t)(4 * tid + j) * NB1 + b];
    s += v[j];
  }
  part[tid] = s;
  __syncthreads();
  // Kogge-Stone inclusive scan over 256 partials
  for (int off = 1; off < 256; off <<= 1) {
    unsigned add = (tid >= off) ? part[tid - off] : 0u;
    __syncthreads();
    part[tid] += add;
    __syncthreads();
  }
  unsigned exc = part[tid] - s;
  #pragma unroll
  for (int j = 0; j < 4; ++j) {
    Mscan1[(size_t)(4 * tid + j) * NB1 + b] = exc;
    exc += v[j];
  }
}

// ---- K5: level-1 scatter with LDS batch-sort -> coalesced segment writes ----
__global__ __launch_bounds__(1024) void k_scatter1(const float* __restrict__ x,
                                                   const int* __restrict__ ind,
                                                   const unsigned* __restrict__ Mscan1,
                                                   const unsigned* __restrict__ fb,
                                                   uint2* __restrict__ P1) {
  __shared__ uint2    sbuf[BATCH];   // 64 KB
  __shared__ unsigned hist[NB1], sbase[NB1], cur[NB1];
  const int t = blockIdx.x;
  if (threadIdx.x < NB1)
    cur[threadIdx.x] = fb[threadIdx.x * FPC] + Mscan1[(size_t)t * NB1 + threadIdx.x];
  const i32x4* pi = reinterpret_cast<const i32x4*>(ind) + (size_t)t * PT4;
  const f32x4* pv = reinterpret_cast<const f32x4*>(x)  + (size_t)t * PT4;

  for (int bt = 0; bt < PT / BATCH; ++bt) {           // 4 batches
    const int v0 = bt * (BATCH / 4);                  // vec4 base of batch
    i32x4 iA = pi[v0 + threadIdx.x];
    f32x4 vA = __builtin_nontemporal_load(pv + v0 + threadIdx.x);
    i32x4 iB = pi[v0 + 1024 + threadIdx.x];
    f32x4 vB = __builtin_nontemporal_load(pv + v0 + 1024 + threadIdx.x);
    if (threadIdx.x < NB1) hist[threadIdx.x] = 0;
    __syncthreads();
    unsigned rA0 = atomicAdd(&hist[(unsigned)iA.x >> CSH], 1u);
    unsigned rA1 = atomicAdd(&hist[(unsigned)iA.y >> CSH], 1u);
    unsigned rA2 = atomicAdd(&hist[(unsigned)iA.z >> CSH], 1u);
    unsigned rA3 = atomicAdd(&hist[(unsigned)iA.w >> CSH], 1u);
    unsigned rB0 = atomicAdd(&hist[(unsigned)iB.x >> CSH], 1u);
    unsigned rB1 = atomicAdd(&hist[(unsigned)iB.y >> CSH], 1u);
    unsigned rB2 = atomicAdd(&hist[(unsigned)iB.z >> CSH], 1u);
    unsigned rB3 = atomicAdd(&hist[(unsigned)iB.w >> CSH], 1u);
    __syncthreads();
    if (threadIdx.x < 64) {   // exclusive scan of hist[256], one wave
      const unsigned lane = threadIdx.x;
      unsigned h0 = hist[4 * lane], h1 = hist[4 * lane + 1];
      unsigned h2 = hist[4 * lane + 2], h3 = hist[4 * lane + 3];
      unsigned sum = h0 + h1 + h2 + h3;
      unsigned inc = sum;
      for (int off = 1; off < 64; off <<= 1) {
        unsigned o = __shfl_up(inc, off, 64);
        if (lane >= (unsigned)off) inc += o;
      }
      unsigned exc = inc - sum;
      sbase[4 * lane]     = exc;
      sbase[4 * lane + 1] = exc + h0;
      sbase[4 * lane + 2] = exc + h0 + h1;
      sbase[4 * lane + 3] = exc + h0 + h1 + h2;
    }
    __syncthreads();
    sbuf[sbase[(unsigned)iA.x >> CSH] + rA0] = make_uint2(__float_as_uint(vA.x), (unsigned)iA.x);
    sbuf[sbase[(unsigned)iA.y >> CSH] + rA1] = make_uint2(__float_as_uint(vA.y), (unsigned)iA.y);
    sbuf[sbase[(unsigned)iA.z >> CSH] + rA2] = make_uint2(__float_as_uint(vA.z), (unsigned)iA.z);
    sbuf[sbase[(unsigned)iA.w >> CSH] + rA3] = make_uint2(__float_as_uint(vA.w), (unsigned)iA.w);
    sbuf[sbase[(unsigned)iB.x >> CSH] + rB0] = make_uint2(__float_as_uint(vB.x), (unsigned)iB.x);
    sbuf[sbase[(unsigned)iB.y >> CSH] + rB1] = make_uint2(__float_as_uint(vB.y), (unsigned)iB.y);
    sbuf[sbase[(unsigned)iB.z >> CSH] + rB2] = make_uint2(__float_as_uint(vB.z), (unsigned)iB.z);
    sbuf[sbase[(unsigned)iB.w >> CSH] + rB3] = make_uint2(__float_as_uint(vB.w), (unsigned)iB.w);
    __syncthreads();
    #pragma unroll
    for (int k = 0; k < BATCH / 1024; ++k) {
      unsigned j = (unsigned)(k * 1024 + threadIdx.x);
      uint2 q = sbuf[j];
      unsigned b = q.y >> CSH;
      P1[cur[b] + (j - sbase[b])] = q;   // cacheable: P1 re-read by scatter2
    }
    __syncthreads();
    if (threadIdx.x < NB1) cur[threadIdx.x] += hist[threadIdx.x];
    __syncthreads();
  }
}

// ---- K6: level-2 scatter, block per coarse bucket, LDS batch-sort x32 ----
__global__ __launch_bounds__(1024) void k_scatter2(const uint2* __restrict__ P1,
                                                   const unsigned* __restrict__ fb,
                                                   float* __restrict__ vout2,
                                                   unsigned short* __restrict__ lout2) {
  __shared__ uint2    sbuf[BATCH];   // 64 KB
  __shared__ unsigned hist[FPC], sbase[FPC], cur[FPC];
  const int c = blockIdx.x;
  const unsigned s = fb[c * FPC];
  const unsigned e = fb[c * FPC + FPC];
  if (threadIdx.x < FPC) cur[threadIdx.x] = fb[c * FPC + threadIdx.x];

  for (unsigned bs = s; bs < e; bs += BATCH) {
    const unsigned len = min((unsigned)BATCH, e - bs);
    u32x2 p[8]; unsigned r[8];
    if (threadIdx.x < FPC) hist[threadIdx.x] = 0;
    __syncthreads();
    #pragma unroll
    for (int k = 0; k < 8; ++k) {
      unsigned j = (unsigned)threadIdx.x + (unsigned)k * 1024u;
      if (j < len) {
        p[k] = __builtin_nontemporal_load(
                 reinterpret_cast<const u32x2*>(P1) + (bs + j));
        r[k] = atomicAdd(&hist[(p[k].y >> FSH) & (FPC - 1)], 1u);
      }
    }
    __syncthreads();
    if (threadIdx.x < 32) {
      const unsigned lane = threadIdx.x;
      unsigned h = hist[lane];
      unsigned inc = h;
      for (int off = 1; off < 32; off <<= 1) {
        unsigned o = __shfl_up(inc, off, 32);
        if (lane >= (unsigned)off) inc += o;
      }
      sbase[lane] = inc - h;
    }
    __syncthreads();
    #pragma unroll
    for (int k = 0; k < 8; ++k) {
      unsigned j = (unsigned)threadIdx.x + (unsigned)k * 1024u;
      if (j < len)
        sbuf[sbase[(p[k].y >> FSH) & (FPC - 1)] + r[k]] = make_uint2(p[k].x, p[k].y);
    }
    __syncthreads();
    for (unsigned j = threadIdx.x; j < len; j += 1024) {
      uint2 q = sbuf[j];
      unsigned f = (q.y >> FSH) & (FPC - 1);
      unsigned d = cur[f] + (j - sbase[f]);
      vout2[d] = __uint_as_float(q.x);
      lout2[d] = (unsigned short)(q.y & (WFL - 1));
    }
    __syncthreads();
    if (threadIdx.x < FPC) cur[threadIdx.x] += hist[threadIdx.x];
    __syncthreads();
  }
}

// ---- K7: one block per fine window: LDS accumulate + dense write ----
__global__ __launch_bounds__(1024) void k_accum(const float* __restrict__ vout2,
                                                const unsigned short* __restrict__ lout2,
                                                const unsigned* __restrict__ fb,
                                                float* __restrict__ out) {
  __shared__ float w[WFL];  // 64 KB
  const int f = blockIdx.x;
  f32x4* w4 = reinterpret_cast<f32x4*>(w);
  for (int i = threadIdx.x; i < WFL / 4; i += 1024) w4[i] = (f32x4){0.f, 0.f, 0.f, 0.f};
  __syncthreads();
  const unsigned s = fb[f], e = fb[f + 1];
  for (unsigned i = s + threadIdx.x; i < e; i += 1024) {
    float v = __builtin_nontemporal_load(vout2 + i);
    unsigned short l = __builtin_nontemporal_load(lout2 + i);
    atomicAdd(&w[l], v);   // ds_add_f32, CU-local
  }
  __syncthreads();
  f32x4* o = reinterpret_cast<f32x4*>(out + (size_t)f * WFL);
  for (int i = threadIdx.x; i < WFL / 4; i += 1024)
    __builtin_nontemporal_store(w4[i], o + i);
}

// ---- Fallback: plain atomic scatter (measured ~1.77 ms) ----
__global__ __launch_bounds__(256) void unpool_scatter_kernel(
    const float* __restrict__ x, const int* __restrict__ ind,
    float* __restrict__ out, int n4) {
  int i = blockIdx.x * blockDim.x + threadIdx.x;
  if (i >= n4) return;
  f32x4 v  = reinterpret_cast<const f32x4*>(x)[i];
  i32x4 id = reinterpret_cast<const i32x4*>(ind)[i];
  unsafeAtomicAdd(&out[id.x], v.x);
  unsafeAtomicAdd(&out[id.y], v.y);
  unsafeAtomicAdd(&out[id.z], v.z);
  unsafeAtomicAdd(&out[id.w], v.w);
}

extern "C" void kernel_launch(void* const* d_in, const int* in_sizes, int n_in,
                              void* d_out, int out_size, void* d_ws, size_t ws_size,
                              hipStream_t stream) {
  const float* x   = (const float*)d_in[0];
  const int*   ind = (const int*)d_in[1];
  float*       out = (float*)d_out;
  const int n = in_sizes[0];

  // ws layout: M1 | Mscan1 | Mf(u16) | csf | fb | vout2 | lout2 | P1  (~488 MB)
  const size_t szM1  = (size_t)T1 * NB1 * sizeof(unsigned);        // 1 MB
  const size_t szMs  = szM1;                                        // 1 MB
  const size_t szMf  = (size_t)T1 * NBF * sizeof(unsigned short);  // 16.8 MB
  const size_t szCsf = ((size_t)NBF * sizeof(unsigned) + 255) & ~(size_t)255;
  const size_t szFb  = ((size_t)(NBF + 1) * sizeof(unsigned) + 255) & ~(size_t)255;
  const size_t szV2  = (size_t)N_TOT * sizeof(float);              // 134.2 MB
  const size_t szL2  = (size_t)N_TOT * sizeof(unsigned short);     // 67.1 MB
  const size_t szP1  = (size_t)N_TOT * sizeof(uint2);              // 268.4 MB
  const size_t need  = szM1 + szMs + szMf + szCsf + szFb + szV2 + szL2 + szP1;

  const bool shape_ok = (n == N_TOT) && (out_size == OUT_TOT);

  if (!shape_ok || ws_size < need) {
    (void)hipMemsetAsync(d_out, 0, (size_t)out_size * sizeof(float), stream);
    const int n4 = n / 4;
    unpool_scatter_kernel<<<(n4 + 255) / 256, 256, 0, stream>>>(x, ind, out, n4);
    return;
  }

  char* ws = (char*)d_ws;
  unsigned*       M1     = (unsigned*)(ws);
  unsigned*       Mscan1 = (unsigned*)(ws + szM1);
  unsigned short* Mf     = (unsigned short*)(ws + szM1 + szMs);
  unsigned*       csf    = (unsigned*)(ws + szM1 + szMs + szMf);
  unsigned*       fb     = (unsigned*)(ws + szM1 + szMs + szMf + szCsf);
  float*          vout2  = (float*)(ws + szM1 + szMs + szMf + szCsf + szFb);
  unsigned short* lout2  = (unsigned short*)(ws + szM1 + szMs + szMf + szCsf + szFb + szV2);
  uint2*          P1     = (uint2*)(ws + szM1 + szMs + szMf + szCsf + szFb + szV2 + szL2);

  k_hist    <<<T1,        1024, 0, stream>>>(ind, M1, Mf);
  k_colsumf <<<NBF / 256,  256, 0, stream>>>(Mf, csf);
  k_scanfb  <<<1,          256, 0, stream>>>(csf, fb);
  k_colscan1<<<NB1,        256, 0, stream>>>(M1, Mscan1);
  k_scatter1<<<T1,        1024, 0, stream>>>(x, ind, Mscan1, fb, P1);
  k_scatter2<<<NB1,       1024, 0, stream>>>(P1, fb, vout2, lout2);
  k_accum   <<<NBF,       1024, 0, stream>>>(vout2, lout2, fb, out);
  // Output fully covered by dense windows -> no memset needed.
}

// Round 8
// 476.970 us; speedup vs baseline: 3.8440x; 1.1370x over previous
//
#include <hip/hip_runtime.h>

// Max-unpooling scatter-add, one-level coarse radix (1024 buckets) with LDS
// batch-sort, then merged sort2+accumulate: each block holds its bucket's
// pairs IN REGISTERS and sweeps its 512 KB output window in 8 x 64 KB LDS
// sub-passes. No global atomics, no vout2/lout2 round-trip.
//   out = zeros(total); out[ind[i]] += x[i]
// N = 2^25 pairs, OUT = 2^27 floats (536.9 MB).

typedef float    f32x4 __attribute__((ext_vector_type(4)));
typedef int      i32x4 __attribute__((ext_vector_type(4)));
typedef unsigned u32x2 __attribute__((ext_vector_type(2)));

#define N_TOT   (1 << 25)     // input pairs
#define OUT_TOT (1 << 27)     // output floats
#define T1      1024          // scatter tiles
#define PT      (N_TOT / T1)  // 32768 pairs/tile
#define PT4     (PT / 4)      // 8192 vec4/tile
#define NB1     1024          // coarse buckets
#define CSH     17            // coarse = idx >> 17  (window 2^17 floats = 512 KB)
#define SSH     14            // sub-window = (idx >> 14) & 7
#define NSUB    8
#define WFL     16384         // floats per sub-window (64 KB LDS)
#define BATCH   16384         // pairs per sort batch (128 KB LDS sbuf)
#define KREG    72            // pairs/thread in k_waccum (512 thr: cap 36864/bucket)

// ---- K1: per-tile coarse histogram (u16: counts <= PT=32768) ----
__global__ __launch_bounds__(1024) void k_hist(const int* __restrict__ ind,
                                               unsigned short* __restrict__ M1) {
  __shared__ unsigned h[NB1];
  const int t = blockIdx.x;
  h[threadIdx.x] = 0;
  __syncthreads();
  const i32x4* p = reinterpret_cast<const i32x4*>(ind) + (size_t)t * PT4;
  for (int k = threadIdx.x; k < PT4; k += 1024) {
    i32x4 id = p[k];   // cacheable: ind re-read by scatter1 (L3 reuse)
    atomicAdd(&h[(unsigned)id.x >> CSH], 1u);
    atomicAdd(&h[(unsigned)id.y >> CSH], 1u);
    atomicAdd(&h[(unsigned)id.z >> CSH], 1u);
    atomicAdd(&h[(unsigned)id.w >> CSH], 1u);
  }
  __syncthreads();
  M1[(size_t)t * NB1 + threadIdx.x] = (unsigned short)h[threadIdx.x];
}

// ---- K2: per-bucket exclusive scan of M1 over tiles + column sums ----
__global__ __launch_bounds__(256) void k_colscan1(const unsigned short* __restrict__ M1,
                                                  unsigned* __restrict__ Mscan1,
                                                  unsigned* __restrict__ colsum) {
  __shared__ unsigned part[256];
  const int b = blockIdx.x;
  const int tid = threadIdx.x;
  unsigned v[4];
  unsigned s = 0;
  #pragma unroll
  for (int j = 0; j < 4; ++j) {
    v[j] = M1[(size_t)(4 * tid + j) * NB1 + b];
    s += v[j];
  }
  part[tid] = s;
  __syncthreads();
  for (int off = 1; off < 256; off <<= 1) {
    unsigned add = (tid >= off) ? part[tid - off] : 0u;
    __syncthreads();
    part[tid] += add;
    __syncthreads();
  }
  unsigned exc = part[tid] - s;
  #pragma unroll
  for (int j = 0; j < 4; ++j) {
    Mscan1[(size_t)(4 * tid + j) * NB1 + b] = exc;
    exc += v[j];
  }
  if (tid == 255) colsum[b] = part[255];
}

// ---- K3: exclusive scan colsum[1024] -> cb[1025] ----
__global__ __launch_bounds__(256) void k_scancb(const unsigned* __restrict__ colsum,
                                                unsigned* __restrict__ cb) {
  __shared__ unsigned part[256];
  const int tid = threadIdx.x;
  unsigned loc[4];
  unsigned s = 0;
  #pragma unroll
  for (int j = 0; j < 4; ++j) { loc[j] = colsum[4 * tid + j]; s += loc[j]; }
  part[tid] = s;
  __syncthreads();
  for (int off = 1; off < 256; off <<= 1) {
    unsigned add = (tid >= off) ? part[tid - off] : 0u;
    __syncthreads();
    part[tid] += add;
    __syncthreads();
  }
  unsigned exc = part[tid] - s;
  #pragma unroll
  for (int j = 0; j < 4; ++j) { cb[4 * tid + j] = exc; exc += loc[j]; }
  if (tid == 255) cb[NB1] = part[255];  // == N_TOT
}

// ---- K4: coarse scatter with LDS batch-sort -> coalesced segment writes ----
__global__ __launch_bounds__(1024) void k_scatter1(const float* __restrict__ x,
                                                   const int* __restrict__ ind,
                                                   const unsigned* __restrict__ Mscan1,
                                                   const unsigned* __restrict__ cb,
                                                   u32x2* __restrict__ P1) {
  __shared__ u32x2    sbuf[BATCH];                 // 128 KB
  __shared__ unsigned hist[NB1], sbase[NB1], cur[NB1];  // 12 KB
  const int t = blockIdx.x;
  cur[threadIdx.x] = cb[threadIdx.x] + Mscan1[(size_t)t * NB1 + threadIdx.x];
  const i32x4* pi = reinterpret_cast<const i32x4*>(ind) + (size_t)t * PT4;
  const f32x4* pv = reinterpret_cast<const f32x4*>(x)  + (size_t)t * PT4;

  for (int bt = 0; bt < PT / BATCH; ++bt) {        // 2 batches
    const int v0 = bt * (BATCH / 4);
    i32x4 iA = pi[v0 + threadIdx.x];
    f32x4 vA = __builtin_nontemporal_load(pv + v0 + threadIdx.x);
    i32x4 iB = pi[v0 + 1024 + threadIdx.x];
    f32x4 vB = __builtin_nontemporal_load(pv + v0 + 1024 + threadIdx.x);
    i32x4 iC = pi[v0 + 2048 + threadIdx.x];
    f32x4 vC = __builtin_nontemporal_load(pv + v0 + 2048 + threadIdx.x);
    i32x4 iD = pi[v0 + 3072 + threadIdx.x];
    f32x4 vD = __builtin_nontemporal_load(pv + v0 + 3072 + threadIdx.x);
    hist[threadIdx.x] = 0;
    __syncthreads();
    unsigned rA0 = atomicAdd(&hist[(unsigned)iA.x >> CSH], 1u);
    unsigned rA1 = atomicAdd(&hist[(unsigned)iA.y >> CSH], 1u);
    unsigned rA2 = atomicAdd(&hist[(unsigned)iA.z >> CSH], 1u);
    unsigned rA3 = atomicAdd(&hist[(unsigned)iA.w >> CSH], 1u);
    unsigned rB0 = atomicAdd(&hist[(unsigned)iB.x >> CSH], 1u);
    unsigned rB1 = atomicAdd(&hist[(unsigned)iB.y >> CSH], 1u);
    unsigned rB2 = atomicAdd(&hist[(unsigned)iB.z >> CSH], 1u);
    unsigned rB3 = atomicAdd(&hist[(unsigned)iB.w >> CSH], 1u);
    unsigned rC0 = atomicAdd(&hist[(unsigned)iC.x >> CSH], 1u);
    unsigned rC1 = atomicAdd(&hist[(unsigned)iC.y >> CSH], 1u);
    unsigned rC2 = atomicAdd(&hist[(unsigned)iC.z >> CSH], 1u);
    unsigned rC3 = atomicAdd(&hist[(unsigned)iC.w >> CSH], 1u);
    unsigned rD0 = atomicAdd(&hist[(unsigned)iD.x >> CSH], 1u);
    unsigned rD1 = atomicAdd(&hist[(unsigned)iD.y >> CSH], 1u);
    unsigned rD2 = atomicAdd(&hist[(unsigned)iD.z >> CSH], 1u);
    unsigned rD3 = atomicAdd(&hist[(unsigned)iD.w >> CSH], 1u);
    __syncthreads();
    if (threadIdx.x < 64) {   // exclusive scan of hist[1024]: 16 entries/lane
      const unsigned lane = threadIdx.x;
      unsigned h[16], sum = 0;
      #pragma unroll
      for (int j = 0; j < 16; ++j) { h[j] = hist[16 * lane + j]; sum += h[j]; }
      unsigned inc = sum;
      for (int off = 1; off < 64; off <<= 1) {
        unsigned o = __shfl_up(inc, off, 64);
        if (lane >= (unsigned)off) inc += o;
      }
      unsigned exc = inc - sum;
      #pragma unroll
      for (int j = 0; j < 16; ++j) { sbase[16 * lane + j] = exc; exc += h[j]; }
    }
    __syncthreads();
    sbuf[sbase[(unsigned)iA.x >> CSH] + rA0] = (u32x2){__float_as_uint(vA.x), (unsigned)iA.x};
    sbuf[sbase[(unsigned)iA.y >> CSH] + rA1] = (u32x2){__float_as_uint(vA.y), (unsigned)iA.y};
    sbuf[sbase[(unsigned)iA.z >> CSH] + rA2] = (u32x2){__float_as_uint(vA.z), (unsigned)iA.z};
    sbuf[sbase[(unsigned)iA.w >> CSH] + rA3] = (u32x2){__float_as_uint(vA.w), (unsigned)iA.w};
    sbuf[sbase[(unsigned)iB.x >> CSH] + rB0] = (u32x2){__float_as_uint(vB.x), (unsigned)iB.x};
    sbuf[sbase[(unsigned)iB.y >> CSH] + rB1] = (u32x2){__float_as_uint(vB.y), (unsigned)iB.y};
    sbuf[sbase[(unsigned)iB.z >> CSH] + rB2] = (u32x2){__float_as_uint(vB.z), (unsigned)iB.z};
    sbuf[sbase[(unsigned)iB.w >> CSH] + rB3] = (u32x2){__float_as_uint(vB.w), (unsigned)iB.w};
    sbuf[sbase[(unsigned)iC.x >> CSH] + rC0] = (u32x2){__float_as_uint(vC.x), (unsigned)iC.x};
    sbuf[sbase[(unsigned)iC.y >> CSH] + rC1] = (u32x2){__float_as_uint(vC.y), (unsigned)iC.y};
    sbuf[sbase[(unsigned)iC.z >> CSH] + rC2] = (u32x2){__float_as_uint(vC.z), (unsigned)iC.z};
    sbuf[sbase[(unsigned)iC.w >> CSH] + rC3] = (u32x2){__float_as_uint(vC.w), (unsigned)iC.w};
    sbuf[sbase[(unsigned)iD.x >> CSH] + rD0] = (u32x2){__float_as_uint(vD.x), (unsigned)iD.x};
    sbuf[sbase[(unsigned)iD.y >> CSH] + rD1] = (u32x2){__float_as_uint(vD.y), (unsigned)iD.y};
    sbuf[sbase[(unsigned)iD.z >> CSH] + rD2] = (u32x2){__float_as_uint(vD.z), (unsigned)iD.z};
    sbuf[sbase[(unsigned)iD.w >> CSH] + rD3] = (u32x2){__float_as_uint(vD.w), (unsigned)iD.w};
    __syncthreads();
    #pragma unroll
    for (int k = 0; k < BATCH / 1024; ++k) {        // 16 coalesced stores
      unsigned j = (unsigned)(k * 1024 + threadIdx.x);
      u32x2 q = sbuf[j];
      unsigned b = q.y >> CSH;
      P1[cur[b] + (j - sbase[b])] = q;   // cacheable: re-read by waccum (L3)
    }
    __syncthreads();
    cur[threadIdx.x] += hist[threadIdx.x];
    __syncthreads();
  }
}

// ---- K5: merged sort2+accum. Block c: pairs in regs, 8 x 64 KB LDS sweeps ----
__global__ __launch_bounds__(512) void k_waccum(const u32x2* __restrict__ P1,
                                                const unsigned* __restrict__ cb,
                                                float* __restrict__ out) {
  __shared__ float w[WFL];   // 64 KB
  const int c = blockIdx.x;
  const unsigned s = cb[c], e = cb[c + 1];
  const unsigned len = e - s;
  const u32x2* P = P1 + s;
  u32x2 p[KREG];
  #pragma unroll
  for (int k = 0; k < KREG; ++k) {
    unsigned j = (unsigned)(k * 512) + threadIdx.x;
    if (j < len) {
      p[k] = P[j];
    } else {
      // harmless sentinel: adds 0.0f into sub 0 at scattered slots
      p[k] = (u32x2){0u, ((unsigned)c << CSH) | (threadIdx.x & (WFL - 1))};
    }
  }
  f32x4* w4 = reinterpret_cast<f32x4*>(w);
  for (int sub = 0; sub < NSUB; ++sub) {
    for (int i = threadIdx.x; i < WFL / 4; i += 512) w4[i] = (f32x4){0.f, 0.f, 0.f, 0.f};
    __syncthreads();
    #pragma unroll
    for (int k = 0; k < KREG; ++k) {
      if (((p[k].y >> SSH) & (NSUB - 1)) == (unsigned)sub)
        atomicAdd(&w[p[k].y & (WFL - 1)], __uint_as_float(p[k].x));  // ds_add_f32
    }
    // tail safety (len > KREG*512: ~never for this input, correct always)
    for (unsigned j = (unsigned)(KREG * 512) + threadIdx.x; j < len; j += 512) {
      u32x2 q = P[j];
      if (((q.y >> SSH) & (NSUB - 1)) == (unsigned)sub)
        atomicAdd(&w[q.y & (WFL - 1)], __uint_as_float(q.x));
    }
    __syncthreads();
    f32x4* o = reinterpret_cast<f32x4*>(out + ((size_t)c << CSH) + ((size_t)sub << SSH));
    for (int i = threadIdx.x; i < WFL / 4; i += 512)
      __builtin_nontemporal_store(w4[i], o + i);
    __syncthreads();
  }
}

// ---- Fallback: plain atomic scatter (measured ~1.77 ms) ----
__global__ __launch_bounds__(256) void unpool_scatter_kernel(
    const float* __restrict__ x, const int* __restrict__ ind,
    float* __restrict__ out, int n4) {
  int i = blockIdx.x * blockDim.x + threadIdx.x;
  if (i >= n4) return;
  f32x4 v  = reinterpret_cast<const f32x4*>(x)[i];
  i32x4 id = reinterpret_cast<const i32x4*>(ind)[i];
  unsafeAtomicAdd(&out[id.x], v.x);
  unsafeAtomicAdd(&out[id.y], v.y);
  unsafeAtomicAdd(&out[id.z], v.z);
  unsafeAtomicAdd(&out[id.w], v.w);
}

extern "C" void kernel_launch(void* const* d_in, const int* in_sizes, int n_in,
                              void* d_out, int out_size, void* d_ws, size_t ws_size,
                              hipStream_t stream) {
  const float* x   = (const float*)d_in[0];
  const int*   ind = (const int*)d_in[1];
  float*       out = (float*)d_out;
  const int n = in_sizes[0];

  // ws layout: M1(u16) | Mscan1(u32) | colsum | cb | P1  (~275 MB)
  const size_t szM1  = (size_t)T1 * NB1 * sizeof(unsigned short);  // 2 MB
  const size_t szMs  = (size_t)T1 * NB1 * sizeof(unsigned);        // 4 MB
  const size_t szCs  = ((size_t)NB1 * sizeof(unsigned) + 255) & ~(size_t)255;
  const size_t szCb  = ((size_t)(NB1 + 1) * sizeof(unsigned) + 255) & ~(size_t)255;
  const size_t szP1  = (size_t)N_TOT * sizeof(u32x2);              // 268.4 MB
  const size_t need  = szM1 + szMs + szCs + szCb + szP1;

  const bool shape_ok = (n == N_TOT) && (out_size == OUT_TOT);

  if (!shape_ok || ws_size < need) {
    (void)hipMemsetAsync(d_out, 0, (size_t)out_size * sizeof(float), stream);
    const int n4 = n / 4;
    unpool_scatter_kernel<<<(n4 + 255) / 256, 256, 0, stream>>>(x, ind, out, n4);
    return;
  }

  char* ws = (char*)d_ws;
  unsigned short* M1     = (unsigned short*)(ws);
  unsigned*       Mscan1 = (unsigned*)(ws + szM1);
  unsigned*       colsum = (unsigned*)(ws + szM1 + szMs);
  unsigned*       cb     = (unsigned*)(ws + szM1 + szMs + szCs);
  u32x2*          P1     = (u32x2*)(ws + szM1 + szMs + szCs + szCb);

  k_hist    <<<T1,  1024, 0, stream>>>(ind, M1);
  k_colscan1<<<NB1,  256, 0, stream>>>(M1, Mscan1, colsum);
  k_scancb  <<<1,    256, 0, stream>>>(colsum, cb);
  k_scatter1<<<T1,  1024, 0, stream>>>(x, ind, Mscan1, cb, P1);
  k_waccum  <<<NB1,  512, 0, stream>>>(P1, cb, out);
  // Output fully covered by dense windows -> no memset needed.
}

// Round 9
// 473.371 us; speedup vs baseline: 3.8733x; 1.0076x over previous
//
#include <hip/hip_runtime.h>

// Max-unpooling scatter-add, one-level coarse radix (1024 buckets) with LDS
// batch-sort, then merged sort2+accumulate (pairs in registers, 8 x 64 KB LDS
// window sweeps). No global atomics.
//   out = zeros(total); out[ind[i]] += x[i]
// N = 2^25 pairs, OUT = 2^27 floats (536.9 MB).
//
// R9: (1) scatter1 loads BOTH its batches up-front so batch-1's global reads
// overlap batch-0's LDS sort + segment stores (1 block/CU -> no TLP to hide
// latency otherwise); (2) waccum at 1024 threads (32 waves/CU with 2 blocks)
// and KREG 72->36 (halves the 8-sweep predicate overhead).

typedef float    f32x4 __attribute__((ext_vector_type(4)));
typedef int      i32x4 __attribute__((ext_vector_type(4)));
typedef unsigned u32x2 __attribute__((ext_vector_type(2)));

#define N_TOT   (1 << 25)     // input pairs
#define OUT_TOT (1 << 27)     // output floats
#define T1      1024          // scatter tiles
#define PT      (N_TOT / T1)  // 32768 pairs/tile
#define PT4     (PT / 4)      // 8192 vec4/tile
#define NB1     1024          // coarse buckets
#define CSH     17            // coarse = idx >> 17  (window 2^17 floats = 512 KB)
#define SSH     14            // sub-window = (idx >> 14) & 7
#define NSUB    8
#define WFL     16384         // floats per sub-window (64 KB LDS)
#define BATCH   16384         // pairs per sort batch (128 KB LDS sbuf)
#define KREG    36            // pairs/thread in k_waccum (1024 thr: cap 36864)

// ---- K1: per-tile coarse histogram (u16: counts <= PT=32768) ----
__global__ __launch_bounds__(1024) void k_hist(const int* __restrict__ ind,
                                               unsigned short* __restrict__ M1) {
  __shared__ unsigned h[NB1];
  const int t = blockIdx.x;
  h[threadIdx.x] = 0;
  __syncthreads();
  const i32x4* p = reinterpret_cast<const i32x4*>(ind) + (size_t)t * PT4;
  for (int k = threadIdx.x; k < PT4; k += 1024) {
    i32x4 id = p[k];   // cacheable: ind re-read by scatter1 (L3 reuse)
    atomicAdd(&h[(unsigned)id.x >> CSH], 1u);
    atomicAdd(&h[(unsigned)id.y >> CSH], 1u);
    atomicAdd(&h[(unsigned)id.z >> CSH], 1u);
    atomicAdd(&h[(unsigned)id.w >> CSH], 1u);
  }
  __syncthreads();
  M1[(size_t)t * NB1 + threadIdx.x] = (unsigned short)h[threadIdx.x];
}

// ---- K2: per-bucket exclusive scan of M1 over tiles + column sums ----
__global__ __launch_bounds__(256) void k_colscan1(const unsigned short* __restrict__ M1,
                                                  unsigned* __restrict__ Mscan1,
                                                  unsigned* __restrict__ colsum) {
  __shared__ unsigned part[256];
  const int b = blockIdx.x;
  const int tid = threadIdx.x;
  unsigned v[4];
  unsigned s = 0;
  #pragma unroll
  for (int j = 0; j < 4; ++j) {
    v[j] = M1[(size_t)(4 * tid + j) * NB1 + b];
    s += v[j];
  }
  part[tid] = s;
  __syncthreads();
  for (int off = 1; off < 256; off <<= 1) {
    unsigned add = (tid >= off) ? part[tid - off] : 0u;
    __syncthreads();
    part[tid] += add;
    __syncthreads();
  }
  unsigned exc = part[tid] - s;
  #pragma unroll
  for (int j = 0; j < 4; ++j) {
    Mscan1[(size_t)(4 * tid + j) * NB1 + b] = exc;
    exc += v[j];
  }
  if (tid == 255) colsum[b] = part[255];
}

// ---- K3: exclusive scan colsum[1024] -> cb[1025] ----
__global__ __launch_bounds__(256) void k_scancb(const unsigned* __restrict__ colsum,
                                                unsigned* __restrict__ cb) {
  __shared__ unsigned part[256];
  const int tid = threadIdx.x;
  unsigned loc[4];
  unsigned s = 0;
  #pragma unroll
  for (int j = 0; j < 4; ++j) { loc[j] = colsum[4 * tid + j]; s += loc[j]; }
  part[tid] = s;
  __syncthreads();
  for (int off = 1; off < 256; off <<= 1) {
    unsigned add = (tid >= off) ? part[tid - off] : 0u;
    __syncthreads();
    part[tid] += add;
    __syncthreads();
  }
  unsigned exc = part[tid] - s;
  #pragma unroll
  for (int j = 0; j < 4; ++j) { cb[4 * tid + j] = exc; exc += loc[j]; }
  if (tid == 255) cb[NB1] = part[255];  // == N_TOT
}

// ---- K4: coarse scatter with LDS batch-sort; both batches prefetched ----
__global__ __launch_bounds__(1024) void k_scatter1(const float* __restrict__ x,
                                                   const int* __restrict__ ind,
                                                   const unsigned* __restrict__ Mscan1,
                                                   const unsigned* __restrict__ cb,
                                                   u32x2* __restrict__ P1) {
  __shared__ u32x2    sbuf[BATCH];                      // 128 KB
  __shared__ unsigned hist[NB1], sbase[NB1], cur[NB1];  // 12 KB
  const int t = blockIdx.x;
  const i32x4* pi = reinterpret_cast<const i32x4*>(ind) + (size_t)t * PT4;
  const f32x4* pv = reinterpret_cast<const f32x4*>(x)  + (size_t)t * PT4;

  // Prefetch BOTH batches up-front: batch-1's 128 KB of global reads stream
  // in while batch-0 runs its LDS sort and segment stores (1 block/CU, no
  // other waves to hide latency). ~64 extra VGPRs; fits at 1024 thr/block.
  i32x4 idx[2][4];
  f32x4 val[2][4];
  #pragma unroll
  for (int bt = 0; bt < 2; ++bt) {
    const int v0 = bt * (BATCH / 4);
    #pragma unroll
    for (int q = 0; q < 4; ++q) {
      idx[bt][q] = pi[v0 + q * 1024 + threadIdx.x];
      val[bt][q] = __builtin_nontemporal_load(pv + v0 + q * 1024 + threadIdx.x);
    }
  }
  cur[threadIdx.x] = cb[threadIdx.x] + Mscan1[(size_t)t * NB1 + threadIdx.x];

  #pragma unroll
  for (int bt = 0; bt < 2; ++bt) {
    hist[threadIdx.x] = 0;
    __syncthreads();
    unsigned r[16];
    #pragma unroll
    for (int q = 0; q < 4; ++q) {
      r[4 * q + 0] = atomicAdd(&hist[(unsigned)idx[bt][q].x >> CSH], 1u);
      r[4 * q + 1] = atomicAdd(&hist[(unsigned)idx[bt][q].y >> CSH], 1u);
      r[4 * q + 2] = atomicAdd(&hist[(unsigned)idx[bt][q].z >> CSH], 1u);
      r[4 * q + 3] = atomicAdd(&hist[(unsigned)idx[bt][q].w >> CSH], 1u);
    }
    __syncthreads();
    if (threadIdx.x < 64) {   // exclusive scan of hist[1024]: 16 entries/lane
      const unsigned lane = threadIdx.x;
      unsigned h[16], sum = 0;
      #pragma unroll
      for (int j = 0; j < 16; ++j) { h[j] = hist[16 * lane + j]; sum += h[j]; }
      unsigned inc = sum;
      for (int off = 1; off < 64; off <<= 1) {
        unsigned o = __shfl_up(inc, off, 64);
        if (lane >= (unsigned)off) inc += o;
      }
      unsigned exc = inc - sum;
      #pragma unroll
      for (int j = 0; j < 16; ++j) { sbase[16 * lane + j] = exc; exc += h[j]; }
    }
    __syncthreads();
    #pragma unroll
    for (int q = 0; q < 4; ++q) {
      sbuf[sbase[(unsigned)idx[bt][q].x >> CSH] + r[4 * q + 0]] =
          (u32x2){__float_as_uint(val[bt][q].x), (unsigned)idx[bt][q].x};
      sbuf[sbase[(unsigned)idx[bt][q].y >> CSH] + r[4 * q + 1]] =
          (u32x2){__float_as_uint(val[bt][q].y), (unsigned)idx[bt][q].y};
      sbuf[sbase[(unsigned)idx[bt][q].z >> CSH] + r[4 * q + 2]] =
          (u32x2){__float_as_uint(val[bt][q].z), (unsigned)idx[bt][q].z};
      sbuf[sbase[(unsigned)idx[bt][q].w >> CSH] + r[4 * q + 3]] =
          (u32x2){__float_as_uint(val[bt][q].w), (unsigned)idx[bt][q].w};
    }
    __syncthreads();
    #pragma unroll
    for (int k = 0; k < BATCH / 1024; ++k) {   // 16 coalesced segment stores
      unsigned j = (unsigned)(k * 1024 + threadIdx.x);
      u32x2 q = sbuf[j];
      unsigned b = q.y >> CSH;
      P1[cur[b] + (j - sbase[b])] = q;
    }
    __syncthreads();
    cur[threadIdx.x] += hist[threadIdx.x];
    __syncthreads();
  }
}

// ---- K5: merged sort2+accum. Pairs in regs, 8 x 64 KB LDS sweeps ----
__global__ __launch_bounds__(1024) void k_waccum(const u32x2* __restrict__ P1,
                                                 const unsigned* __restrict__ cb,
                                                 float* __restrict__ out) {
  __shared__ float w[WFL];   // 64 KB -> 2 blocks/CU, 32 waves/CU
  const int c = blockIdx.x;
  const unsigned s = cb[c], e = cb[c + 1];
  const unsigned len = e - s;
  const u32x2* P = P1 + s;
  u32x2 p[KREG];
  #pragma unroll
  for (int k = 0; k < KREG; ++k) {
    unsigned j = (unsigned)(k * 1024) + threadIdx.x;
    if (j < len) {
      p[k] = P[j];
    } else {
      // harmless sentinel: adds 0.0f into sub 0 at scattered slots
      p[k] = (u32x2){0u, ((unsigned)c << CSH) | (threadIdx.x & (WFL - 1))};
    }
  }
  f32x4* w4 = reinterpret_cast<f32x4*>(w);
  for (int sub = 0; sub < NSUB; ++sub) {
    for (int i = threadIdx.x; i < WFL / 4; i += 1024) w4[i] = (f32x4){0.f, 0.f, 0.f, 0.f};
    __syncthreads();
    #pragma unroll
    for (int k = 0; k < KREG; ++k) {
      if (((p[k].y >> SSH) & (NSUB - 1)) == (unsigned)sub)
        atomicAdd(&w[p[k].y & (WFL - 1)], __uint_as_float(p[k].x));  // ds_add_f32
    }
    // tail safety (len > KREG*1024: ~never for this input, correct always)
    for (unsigned j = (unsigned)(KREG * 1024) + threadIdx.x; j < len; j += 1024) {
      u32x2 q = P[j];
      if (((q.y >> SSH) & (NSUB - 1)) == (unsigned)sub)
        atomicAdd(&w[q.y & (WFL - 1)], __uint_as_float(q.x));
    }
    __syncthreads();
    f32x4* o = reinterpret_cast<f32x4*>(out + ((size_t)c << CSH) + ((size_t)sub << SSH));
    for (int i = threadIdx.x; i < WFL / 4; i += 1024)
      __builtin_nontemporal_store(w4[i], o + i);
    __syncthreads();
  }
}

// ---- Fallback: plain atomic scatter (measured ~1.77 ms) ----
__global__ __launch_bounds__(256) void unpool_scatter_kernel(
    const float* __restrict__ x, const int* __restrict__ ind,
    float* __restrict__ out, int n4) {
  int i = blockIdx.x * blockDim.x + threadIdx.x;
  if (i >= n4) return;
  f32x4 v  = reinterpret_cast<const f32x4*>(x)[i];
  i32x4 id = reinterpret_cast<const i32x4*>(ind)[i];
  unsafeAtomicAdd(&out[id.x], v.x);
  unsafeAtomicAdd(&out[id.y], v.y);
  unsafeAtomicAdd(&out[id.z], v.z);
  unsafeAtomicAdd(&out[id.w], v.w);
}

extern "C" void kernel_launch(void* const* d_in, const int* in_sizes, int n_in,
                              void* d_out, int out_size, void* d_ws, size_t ws_size,
                              hipStream_t stream) {
  const float* x   = (const float*)d_in[0];
  const int*   ind = (const int*)d_in[1];
  float*       out = (float*)d_out;
  const int n = in_sizes[0];

  // ws layout: M1(u16) | Mscan1(u32) | colsum | cb | P1  (~275 MB)
  const size_t szM1  = (size_t)T1 * NB1 * sizeof(unsigned short);  // 2 MB
  const size_t szMs  = (size_t)T1 * NB1 * sizeof(unsigned);        // 4 MB
  const size_t szCs  = ((size_t)NB1 * sizeof(unsigned) + 255) & ~(size_t)255;
  const size_t szCb  = ((size_t)(NB1 + 1) * sizeof(unsigned) + 255) & ~(size_t)255;
  const size_t szP1  = (size_t)N_TOT * sizeof(u32x2);              // 268.4 MB
  const size_t need  = szM1 + szMs + szCs + szCb + szP1;

  const bool shape_ok = (n == N_TOT) && (out_size == OUT_TOT);

  if (!shape_ok || ws_size < need) {
    (void)hipMemsetAsync(d_out, 0, (size_t)out_size * sizeof(float), stream);
    const int n4 = n / 4;
    unpool_scatter_kernel<<<(n4 + 255) / 256, 256, 0, stream>>>(x, ind, out, n4);
    return;
  }

  char* ws = (char*)d_ws;
  unsigned short* M1     = (unsigned short*)(ws);
  unsigned*       Mscan1 = (unsigned*)(ws + szM1);
  unsigned*       colsum = (unsigned*)(ws + szM1 + szMs);
  unsigned*       cb     = (unsigned*)(ws + szM1 + szMs + szCs);
  u32x2*          P1     = (u32x2*)(ws + szM1 + szMs + szCs + szCb);

  k_hist    <<<T1,  1024, 0, stream>>>(ind, M1);
  k_colscan1<<<NB1,  256, 0, stream>>>(M1, Mscan1, colsum);
  k_scancb  <<<1,    256, 0, stream>>>(colsum, cb);
  k_scatter1<<<T1,  1024, 0, stream>>>(x, ind, Mscan1, cb, P1);
  k_waccum  <<<NB1, 1024, 0, stream>>>(P1, cb, out);
  // Output fully covered by dense windows -> no memset needed.
}